// Round 1
// baseline (212.811 us; speedup 1.0000x reference)
//
#include <hip/hip_runtime.h>
#include <math.h>

// Problem constants (from reference)
#define B_   128
#define LQ_  64
#define LD_  512
#define E_   300
#define K_   11
#define TE   16     // E-slice staged per tile
#define NCH  4      // d-chunks per batch
#define DCH  128    // LD_/NCH

// RBF kernel constants: mu list = 1.0, 0.9, 0.7, ..., -0.9 ; sigma = 0.001, then 0.1 x10
// NEGC[k] = -1/(2*sigma_k^2)
__device__ __constant__ float MU_C[K_] =
    {1.0f, 0.9f, 0.7f, 0.5f, 0.3f, 0.1f, -0.1f, -0.3f, -0.5f, -0.7f, -0.9f};
__device__ __constant__ float NEGC_C[K_] =
    {-500000.0f, -50.0f, -50.0f, -50.0f, -50.0f, -50.0f,
     -50.0f, -50.0f, -50.0f, -50.0f, -50.0f};

// Main fused kernel: per (batch, d-chunk) block computes S = Q·D^T for its chunk,
// normalizes via fused row-norms, applies RBF pooling, writes partial pooling
// sums [B][NCH][LQ][K] into workspace.
__global__ __launch_bounds__(256) void knrm_main(
    const float* __restrict__ Q, const float* __restrict__ D,
    const float* __restrict__ mask_d, float* __restrict__ psum)
{
    const int b   = blockIdx.y;
    const int ch  = blockIdx.x;
    const int d0  = ch * DCH;
    const int tid = threadIdx.x;
    const int tx  = tid & 15;   // d-tile owner (8 docs)
    const int ty  = tid >> 4;   // q-tile owner (4 queries)

    __shared__ float Qs[TE][LQ_];
    __shared__ float Ds[TE][DCH];
    __shared__ float qinv_s[LQ_];
    __shared__ float dinv_s[DCH];

    // staging map: 4 threads per q-row (4 floats each), 2 threads per d-row (8 floats each)
    const int sq_q = tid >> 2;
    const int sq_e = (tid & 3) << 2;
    const int sd_d = tid >> 1;
    const int sd_e = (tid & 1) << 3;

    const float* qp = Q + ((size_t)b * LQ_ + sq_q) * E_ + sq_e;
    const float* dp = D + ((size_t)b * LD_ + d0 + sd_d) * E_ + sd_e;

    float acc[4][8];
#pragma unroll
    for (int i = 0; i < 4; ++i)
#pragma unroll
        for (int j = 0; j < 8; ++j) acc[i][j] = 0.0f;

    float ssq = 0.0f;  // partial sum-of-squares for q-row sq_q
    float ssd = 0.0f;  // partial sum-of-squares for d-row sd_d

    for (int e0 = 0; e0 < E_; e0 += TE) {
        float4 qv  = make_float4(0.f, 0.f, 0.f, 0.f);
        float4 dv0 = make_float4(0.f, 0.f, 0.f, 0.f);
        float4 dv1 = make_float4(0.f, 0.f, 0.f, 0.f);
        if (e0 + sq_e + 4 <= E_) qv  = *(const float4*)(qp + e0);
        if (e0 + sd_e + 4 <= E_) dv0 = *(const float4*)(dp + e0);
        if (e0 + sd_e + 8 <= E_) dv1 = *(const float4*)(dp + e0 + 4);

        __syncthreads();  // previous tile fully consumed
        Qs[sq_e + 0][sq_q] = qv.x;
        Qs[sq_e + 1][sq_q] = qv.y;
        Qs[sq_e + 2][sq_q] = qv.z;
        Qs[sq_e + 3][sq_q] = qv.w;
        Ds[sd_e + 0][sd_d] = dv0.x;
        Ds[sd_e + 1][sd_d] = dv0.y;
        Ds[sd_e + 2][sd_d] = dv0.z;
        Ds[sd_e + 3][sd_d] = dv0.w;
        Ds[sd_e + 4][sd_d] = dv1.x;
        Ds[sd_e + 5][sd_d] = dv1.y;
        Ds[sd_e + 6][sd_d] = dv1.z;
        Ds[sd_e + 7][sd_d] = dv1.w;
        ssq += qv.x * qv.x + qv.y * qv.y + qv.z * qv.z + qv.w * qv.w;
        ssd += dv0.x * dv0.x + dv0.y * dv0.y + dv0.z * dv0.z + dv0.w * dv0.w;
        ssd += dv1.x * dv1.x + dv1.y * dv1.y + dv1.z * dv1.z + dv1.w * dv1.w;
        __syncthreads();

#pragma unroll
        for (int e = 0; e < TE; ++e) {
            float4 a  = *(const float4*)&Qs[e][ty << 2];
            float4 b0 = *(const float4*)&Ds[e][tx << 3];
            float4 b1 = *(const float4*)&Ds[e][(tx << 3) + 4];
            float av[4] = {a.x, a.y, a.z, a.w};
            float bv[8] = {b0.x, b0.y, b0.z, b0.w, b1.x, b1.y, b1.z, b1.w};
#pragma unroll
            for (int i = 0; i < 4; ++i)
#pragma unroll
                for (int j = 0; j < 8; ++j) acc[i][j] += av[i] * bv[j];
        }
    }

    // finish row norms: q-row shared by 4 consecutive lanes, d-row by 2
    ssq += __shfl_xor(ssq, 1);
    ssq += __shfl_xor(ssq, 2);
    if ((tid & 3) == 0) qinv_s[sq_q] = 1.0f / fmaxf(sqrtf(ssq), 1e-12f);
    ssd += __shfl_xor(ssd, 1);
    if ((tid & 1) == 0) dinv_s[sd_d] = 1.0f / fmaxf(sqrtf(ssd), 1e-12f);
    __syncthreads();

    float qi[4], di[8], md[8];
#pragma unroll
    for (int i = 0; i < 4; ++i) qi[i] = qinv_s[(ty << 2) + i];
#pragma unroll
    for (int j = 0; j < 8; ++j) di[j] = dinv_s[(tx << 3) + j];
#pragma unroll
    for (int j = 0; j < 8; ++j)
        md[j] = mask_d[(size_t)b * LD_ + d0 + (tx << 3) + j];

    // RBF pooling: kacc[i][k] = sum over this thread's 8 docs
    float kacc[4][K_];
#pragma unroll
    for (int i = 0; i < 4; ++i)
#pragma unroll
        for (int k = 0; k < K_; ++k) kacc[i][k] = 0.0f;

#pragma unroll
    for (int i = 0; i < 4; ++i) {
#pragma unroll
        for (int j = 0; j < 8; ++j) {
            float s = acc[i][j] * qi[i] * di[j];
#pragma unroll
            for (int k = 0; k < K_; ++k) {
                float df = s - MU_C[k];
                kacc[i][k] += __expf(df * df * NEGC_C[k]) * md[j];
            }
        }
    }

    // reduce over the 16 tx lanes (bits 0-3 of lane id)
#pragma unroll
    for (int m = 8; m >= 1; m >>= 1) {
#pragma unroll
        for (int i = 0; i < 4; ++i)
#pragma unroll
            for (int k = 0; k < K_; ++k)
                kacc[i][k] += __shfl_xor(kacc[i][k], m);
    }

    if (tx == 0) {
#pragma unroll
        for (int i = 0; i < 4; ++i) {
            const size_t base =
                (((size_t)b * NCH + ch) * LQ_ + ((ty << 2) + i)) * K_;
#pragma unroll
            for (int k = 0; k < K_; ++k) psum[base + k] = kacc[i][k];
        }
    }
}

// Final kernel: combine chunk partials, log-pool, dense + tanh. One wave per batch.
__global__ __launch_bounds__(64) void knrm_final(
    const float* __restrict__ psum, const float* __restrict__ mask_q,
    const float* __restrict__ dw, const float* __restrict__ db,
    float* __restrict__ out)
{
    const int b = blockIdx.x;
    const int q = threadIdx.x;  // 0..63

    float t = 0.0f;
#pragma unroll
    for (int k = 0; k < K_; ++k) {
        float p = 0.0f;
#pragma unroll
        for (int c = 0; c < NCH; ++c)
            p += psum[(((size_t)b * NCH + c) * LQ_ + q) * K_ + k];
        p = fmaxf(p, 1e-10f);
        t += logf(p) * dw[k];
    }
    t *= 0.01f * mask_q[(size_t)b * LQ_ + q];

#pragma unroll
    for (int m = 32; m >= 1; m >>= 1) t += __shfl_xor(t, m);
    if (q == 0) out[b] = tanhf(t + db[0]);
}

extern "C" void kernel_launch(void* const* d_in, const int* in_sizes, int n_in,
                              void* d_out, int out_size, void* d_ws, size_t ws_size,
                              hipStream_t stream) {
    const float* Q   = (const float*)d_in[0];  // [B, LQ, E]
    const float* D   = (const float*)d_in[1];  // [B, LD, E]
    const float* mq  = (const float*)d_in[2];  // [B, LQ]
    const float* md  = (const float*)d_in[3];  // [B, LD]
    const float* dw  = (const float*)d_in[4];  // [1, K]
    const float* db  = (const float*)d_in[5];  // [1]
    float* out  = (float*)d_out;               // [B, 1]
    float* psum = (float*)d_ws;                // [B][NCH][LQ][K] partials

    dim3 grid(NCH, B_);
    knrm_main<<<grid, 256, 0, stream>>>(Q, D, md, psum);
    knrm_final<<<B_, 64, 0, stream>>>(psum, mq, dw, db, out);
}

// Round 2
// 154.299 us; speedup vs baseline: 1.3792x; 1.3792x over previous
//
#include <hip/hip_runtime.h>
#include <hip/hip_bf16.h>
#include <math.h>

#define B_   128
#define LQ_  64
#define LD_  512
#define E_   300
#define K_   11
#define NCH  4      // d-chunks per batch
#define DCH  128    // LD_/NCH
#define BK   32     // K-slice per tile
#define NT   10     // k-tiles (covers 320, zero-padded past 300)
#define LSTR 40     // LDS row stride in bf16 elems (32 data + 8 pad -> 80 B, conflict-free)

typedef __bf16  bf16x8  __attribute__((ext_vector_type(8)));
typedef float   floatx4 __attribute__((ext_vector_type(4)));

__device__ __constant__ float MU_C[K_] =
    {1.0f, 0.9f, 0.7f, 0.5f, 0.3f, 0.1f, -0.1f, -0.3f, -0.5f, -0.7f, -0.9f};
__device__ __constant__ float NEGC_C[K_] =
    {-500000.0f, -50.0f, -50.0f, -50.0f, -50.0f, -50.0f,
     -50.0f, -50.0f, -50.0f, -50.0f, -50.0f};

__device__ __forceinline__ unsigned int pk2(float x, float y) {
    __hip_bfloat162 h = __float22bfloat162_rn(make_float2(x, y));
    union { __hip_bfloat162 h2; unsigned int u; } c;
    c.h2 = h;
    return c.u;
}

__device__ __forceinline__ void load8(const float* p, int e, float v[8]) {
    if (e + 8 <= E_) {
        float4 a = *(const float4*)(p + e);
        float4 b = *(const float4*)(p + e + 4);
        v[0] = a.x; v[1] = a.y; v[2] = a.z; v[3] = a.w;
        v[4] = b.x; v[5] = b.y; v[6] = b.z; v[7] = b.w;
    } else {
#pragma unroll
        for (int j = 0; j < 8; ++j) v[j] = (e + j < E_) ? p[e + j] : 0.0f;
    }
}

// Fused bf16-MFMA GEMM + RBF pooling. Block = (batch, d-chunk of 128), 256 thr.
// Wave (wm,wn) computes 32 q-rows x 64 d-cols via 2x4 tiles of 16x16x32 bf16.
__global__ __launch_bounds__(256) void knrm_main(
    const float* __restrict__ Q, const float* __restrict__ D,
    const float* __restrict__ mask_d, float* __restrict__ psum)
{
    const int b = blockIdx.y, ch = blockIdx.x, d0 = ch * DCH;
    const int tid  = threadIdx.x;
    const int lane = tid & 63;
    const int wave = tid >> 6;
    const int wm   = wave >> 1;   // q-half (0..1): rows wm*32..+31
    const int wn   = wave & 1;    // d-half (0..1): cols wn*64..+63
    const int quad = lane >> 4;
    const int l15  = lane & 15;

    __shared__ __align__(16) unsigned short Qs[LQ_ * LSTR];
    __shared__ __align__(16) unsigned short Ds[DCH * LSTR];
    __shared__ float qinv_s[LQ_];
    __shared__ float dinv_s[DCH];
    __shared__ float kps[2][LQ_ * K_];

    // staging map: 4 thr/q-row (8 floats each), 2 thr/d-row (16 floats each)
    const int qrow = tid >> 2, qpart = tid & 3;
    const int drow = tid >> 1, dpart = tid & 1;
    const float* qp = Q + ((size_t)b * LQ_ + qrow) * E_;
    const float* dp = D + ((size_t)b * LD_ + d0 + drow) * E_;

    floatx4 acc[2][4];
    floatx4 zero4 = {0.f, 0.f, 0.f, 0.f};
#pragma unroll
    for (int ti = 0; ti < 2; ++ti)
#pragma unroll
        for (int ni = 0; ni < 4; ++ni) acc[ti][ni] = zero4;

    float ssq = 0.f, ssd = 0.f;
    float qv[8], dv[16];
    load8(qp, qpart * 8, qv);
    load8(dp, dpart * 16, dv);
    load8(dp, dpart * 16 + 8, dv + 8);

    for (int t = 0; t < NT; ++t) {
        unsigned int qpk[4], dpk[8];
#pragma unroll
        for (int j = 0; j < 4; ++j) qpk[j] = pk2(qv[2 * j], qv[2 * j + 1]);
#pragma unroll
        for (int j = 0; j < 8; ++j) dpk[j] = pk2(dv[2 * j], dv[2 * j + 1]);
#pragma unroll
        for (int j = 0; j < 8; ++j)  ssq = fmaf(qv[j], qv[j], ssq);
#pragma unroll
        for (int j = 0; j < 16; ++j) ssd = fmaf(dv[j], dv[j], ssd);

        __syncthreads();  // prev tile fully consumed
        *(uint4*)&Qs[qrow * LSTR + qpart * 8] =
            make_uint4(qpk[0], qpk[1], qpk[2], qpk[3]);
        *(uint4*)&Ds[drow * LSTR + dpart * 16] =
            make_uint4(dpk[0], dpk[1], dpk[2], dpk[3]);
        *(uint4*)&Ds[drow * LSTR + dpart * 16 + 8] =
            make_uint4(dpk[4], dpk[5], dpk[6], dpk[7]);
        __syncthreads();

        if (t + 1 < NT) {  // prefetch next tile; loads fly during MFMAs
            int e0 = (t + 1) * BK;
            load8(qp, e0 + qpart * 8, qv);
            load8(dp, e0 + dpart * 16, dv);
            load8(dp, e0 + dpart * 16 + 8, dv + 8);
        }

        bf16x8 af0 = *(const bf16x8*)&Qs[(wm * 32 + l15) * LSTR + quad * 8];
        bf16x8 af1 = *(const bf16x8*)&Qs[(wm * 32 + 16 + l15) * LSTR + quad * 8];
        bf16x8 bfr[4];
#pragma unroll
        for (int ni = 0; ni < 4; ++ni)
            bfr[ni] = *(const bf16x8*)&Ds[(wn * 64 + ni * 16 + l15) * LSTR + quad * 8];
#pragma unroll
        for (int ni = 0; ni < 4; ++ni) {
            acc[0][ni] = __builtin_amdgcn_mfma_f32_16x16x32_bf16(af0, bfr[ni], acc[0][ni], 0, 0, 0);
            acc[1][ni] = __builtin_amdgcn_mfma_f32_16x16x32_bf16(af1, bfr[ni], acc[1][ni], 0, 0, 0);
        }
    }

    // row inv-norms (fp32, accumulated pre-conversion)
    ssq += __shfl_xor(ssq, 1);
    ssq += __shfl_xor(ssq, 2);
    if ((tid & 3) == 0) qinv_s[qrow] = 1.0f / fmaxf(sqrtf(ssq), 1e-12f);
    ssd += __shfl_xor(ssd, 1);
    if ((tid & 1) == 0) dinv_s[drow] = 1.0f / fmaxf(sqrtf(ssd), 1e-12f);
    __syncthreads();

    float di4[4], md4[4];
#pragma unroll
    for (int ni = 0; ni < 4; ++ni) {
        int dc = wn * 64 + ni * 16 + l15;
        di4[ni] = dinv_s[dc];
        md4[ni] = mask_d[(size_t)b * LD_ + d0 + dc];
    }

#pragma unroll
    for (int ti = 0; ti < 2; ++ti) {
        float qi4[4];
#pragma unroll
        for (int r = 0; r < 4; ++r)
            qi4[r] = qinv_s[wm * 32 + ti * 16 + quad * 4 + r];

        float kacc[4][K_];
#pragma unroll
        for (int r = 0; r < 4; ++r)
#pragma unroll
            for (int k = 0; k < K_; ++k) kacc[r][k] = 0.f;

#pragma unroll
        for (int ni = 0; ni < 4; ++ni) {
#pragma unroll
            for (int r = 0; r < 4; ++r) {
                float s = acc[ti][ni][r] * qi4[r] * di4[ni];
#pragma unroll
                for (int k = 0; k < K_; ++k) {
                    float df = s - MU_C[k];
                    kacc[r][k] = fmaf(__expf(df * df * NEGC_C[k]), md4[ni], kacc[r][k]);
                }
            }
        }
        // sum over the 16 d-lanes (low 4 lane bits; quad invariant)
#pragma unroll
        for (int m = 8; m >= 1; m >>= 1)
#pragma unroll
            for (int r = 0; r < 4; ++r)
#pragma unroll
                for (int k = 0; k < K_; ++k)
                    kacc[r][k] += __shfl_xor(kacc[r][k], m);

        if (l15 == 0) {
#pragma unroll
            for (int r = 0; r < 4; ++r) {
                int q = wm * 32 + ti * 16 + quad * 4 + r;
#pragma unroll
                for (int k = 0; k < K_; ++k) kps[wn][q * K_ + k] = kacc[r][k];
            }
        }
    }
    __syncthreads();

    const size_t pbase = ((size_t)b * NCH + ch) * (LQ_ * K_);
    for (int idx = tid; idx < LQ_ * K_; idx += 256)
        psum[pbase + idx] = kps[0][idx] + kps[1][idx];
}

// Combine chunk partials, log-pool, dense + tanh. One wave per batch.
__global__ __launch_bounds__(64) void knrm_final(
    const float* __restrict__ psum, const float* __restrict__ mask_q,
    const float* __restrict__ dw, const float* __restrict__ db,
    float* __restrict__ out)
{
    const int b = blockIdx.x;
    const int q = threadIdx.x;  // 0..63

    float t = 0.0f;
#pragma unroll
    for (int k = 0; k < K_; ++k) {
        float p = 0.0f;
#pragma unroll
        for (int c = 0; c < NCH; ++c)
            p += psum[(((size_t)b * NCH + c) * LQ_ + q) * K_ + k];
        p = fmaxf(p, 1e-10f);
        t += logf(p) * dw[k];
    }
    t *= 0.01f * mask_q[(size_t)b * LQ_ + q];

#pragma unroll
    for (int m = 32; m >= 1; m >>= 1) t += __shfl_xor(t, m);
    if (q == 0) out[b] = tanhf(t + db[0]);
}

extern "C" void kernel_launch(void* const* d_in, const int* in_sizes, int n_in,
                              void* d_out, int out_size, void* d_ws, size_t ws_size,
                              hipStream_t stream) {
    const float* Q   = (const float*)d_in[0];  // [B, LQ, E]
    const float* D   = (const float*)d_in[1];  // [B, LD, E]
    const float* mq  = (const float*)d_in[2];  // [B, LQ]
    const float* md  = (const float*)d_in[3];  // [B, LD]
    const float* dw  = (const float*)d_in[4];  // [1, K]
    const float* db  = (const float*)d_in[5];  // [1]
    float* out  = (float*)d_out;               // [B, 1]
    float* psum = (float*)d_ws;                // [B][NCH][LQ][K]

    dim3 grid(NCH, B_);
    knrm_main<<<grid, 256, 0, stream>>>(Q, D, md, psum);
    knrm_final<<<B_, 64, 0, stream>>>(psum, mq, dw, db, out);
}

// Round 3
// 151.339 us; speedup vs baseline: 1.4062x; 1.0196x over previous
//
#include <hip/hip_runtime.h>
#include <hip/hip_bf16.h>
#include <math.h>

#define B_   128
#define LQ_  64
#define LD_  512
#define E_   300
#define K_   11
#define NCH  8      // d-chunks per batch
#define DCH  64     // LD_/NCH
#define BK   32     // K-slice per tile
#define NT   10     // k-tiles (covers 320, zero-padded past 300)
#define LSTR 40     // LDS row stride in bf16 elems (32 data + 8 pad, conflict-free)

typedef __bf16  bf16x8  __attribute__((ext_vector_type(8)));
typedef float   floatx4 __attribute__((ext_vector_type(4)));

__device__ __constant__ float MU_C[K_] =
    {1.0f, 0.9f, 0.7f, 0.5f, 0.3f, 0.1f, -0.1f, -0.3f, -0.5f, -0.7f, -0.9f};
__device__ __constant__ float NEGC_C[K_] =
    {-500000.0f, -50.0f, -50.0f, -50.0f, -50.0f, -50.0f,
     -50.0f, -50.0f, -50.0f, -50.0f, -50.0f};

__device__ __forceinline__ unsigned int pk2(float x, float y) {
    __hip_bfloat162 h = __float22bfloat162_rn(make_float2(x, y));
    union { __hip_bfloat162 h2; unsigned int u; } c;
    c.h2 = h;
    return c.u;
}

__device__ __forceinline__ void load8(const float* p, int e, float v[8]) {
    if (e + 8 <= E_) {
        float4 a = *(const float4*)(p + e);
        float4 b = *(const float4*)(p + e + 4);
        v[0] = a.x; v[1] = a.y; v[2] = a.z; v[3] = a.w;
        v[4] = b.x; v[5] = b.y; v[6] = b.z; v[7] = b.w;
    } else {
#pragma unroll
        for (int j = 0; j < 8; ++j) v[j] = (e + j < E_) ? p[e + j] : 0.0f;
    }
}

// Fused bf16-MFMA GEMM + RBF pooling. Block = (batch, d-chunk of 64), 256 thr.
// Wave w computes q-rows [w*16, w*16+16) x all 64 d-cols (4 n-tiles 16x16x32).
// Double-buffered LDS: ONE barrier per K-iter.
__global__ __launch_bounds__(256) void knrm_main(
    const float* __restrict__ Q, const float* __restrict__ D,
    const float* __restrict__ mask_d, float* __restrict__ psum)
{
    const int b = blockIdx.y, ch = blockIdx.x, d0 = ch * DCH;
    const int tid  = threadIdx.x;
    const int lane = tid & 63;
    const int wm   = tid >> 6;    // wave -> q-tile (16 rows)
    const int quad = lane >> 4;
    const int l15  = lane & 15;

    __shared__ __align__(16) unsigned short Qs[2][LQ_ * LSTR];
    __shared__ __align__(16) unsigned short Ds[2][DCH * LSTR];
    __shared__ float qinv_s[LQ_];
    __shared__ float dinv_s[DCH];

    // staging map: 4 thr per row, 8 floats each (both Q and D: 64 rows x 32 e)
    const int row  = tid >> 2;
    const int part = tid & 3;
    const float* qp = Q + ((size_t)b * LQ_ + row) * E_;
    const float* dp = D + ((size_t)b * LD_ + d0 + row) * E_;

    floatx4 acc[4];
    floatx4 zero4 = {0.f, 0.f, 0.f, 0.f};
#pragma unroll
    for (int ni = 0; ni < 4; ++ni) acc[ni] = zero4;

    float ssq = 0.f, ssd = 0.f;
    float qv[8], dv[8];

    // preload + stage tile 0 into buffer 0
    load8(qp, part * 8, qv);
    load8(dp, part * 8, dv);
    {
        unsigned int qpk[4], dpk[4];
#pragma unroll
        for (int j = 0; j < 4; ++j) {
            qpk[j] = pk2(qv[2 * j], qv[2 * j + 1]);
            dpk[j] = pk2(dv[2 * j], dv[2 * j + 1]);
        }
#pragma unroll
        for (int j = 0; j < 8; ++j) {
            ssq = fmaf(qv[j], qv[j], ssq);
            ssd = fmaf(dv[j], dv[j], ssd);
        }
        *(uint4*)&Qs[0][row * LSTR + part * 8] = make_uint4(qpk[0], qpk[1], qpk[2], qpk[3]);
        *(uint4*)&Ds[0][row * LSTR + part * 8] = make_uint4(dpk[0], dpk[1], dpk[2], dpk[3]);
    }

    for (int t = 0; t < NT; ++t) {
        const int cur = t & 1;
        if (t + 1 < NT) {  // issue next tile's global loads before the barrier
            int e0 = (t + 1) * BK + part * 8;
            load8(qp, e0, qv);
            load8(dp, e0, dv);
        }
        __syncthreads();  // buf[cur] fully written; prev reads of buf[1-cur] done

        bf16x8 af = *(const bf16x8*)&Qs[cur][(wm * 16 + l15) * LSTR + quad * 8];
        bf16x8 bfr[4];
#pragma unroll
        for (int ni = 0; ni < 4; ++ni)
            bfr[ni] = *(const bf16x8*)&Ds[cur][(ni * 16 + l15) * LSTR + quad * 8];
#pragma unroll
        for (int ni = 0; ni < 4; ++ni)
            acc[ni] = __builtin_amdgcn_mfma_f32_16x16x32_bf16(af, bfr[ni], acc[ni], 0, 0, 0);

        if (t + 1 < NT) {  // convert + store next tile into the other buffer
            unsigned int qpk[4], dpk[4];
#pragma unroll
            for (int j = 0; j < 4; ++j) {
                qpk[j] = pk2(qv[2 * j], qv[2 * j + 1]);
                dpk[j] = pk2(dv[2 * j], dv[2 * j + 1]);
            }
#pragma unroll
            for (int j = 0; j < 8; ++j) {
                ssq = fmaf(qv[j], qv[j], ssq);
                ssd = fmaf(dv[j], dv[j], ssd);
            }
            *(uint4*)&Qs[1 - cur][row * LSTR + part * 8] = make_uint4(qpk[0], qpk[1], qpk[2], qpk[3]);
            *(uint4*)&Ds[1 - cur][row * LSTR + part * 8] = make_uint4(dpk[0], dpk[1], dpk[2], dpk[3]);
        }
    }

    // row inv-norms (fp32, accumulated pre-conversion); 4 staging lanes per row
    ssq += __shfl_xor(ssq, 1);
    ssq += __shfl_xor(ssq, 2);
    ssd += __shfl_xor(ssd, 1);
    ssd += __shfl_xor(ssd, 2);
    if (part == 0) {
        qinv_s[row] = 1.0f / fmaxf(sqrtf(ssq), 1e-12f);
        dinv_s[row] = 1.0f / fmaxf(sqrtf(ssd), 1e-12f);
    }
    __syncthreads();

    float qi[4], di[4], md[4];
#pragma unroll
    for (int r = 0; r < 4; ++r) qi[r] = qinv_s[wm * 16 + quad * 4 + r];
#pragma unroll
    for (int ni = 0; ni < 4; ++ni) {
        int dc = ni * 16 + l15;
        di[ni] = dinv_s[dc];
        md[ni] = mask_d[(size_t)b * LD_ + d0 + dc];
    }

    float kacc[4][K_];
#pragma unroll
    for (int r = 0; r < 4; ++r)
#pragma unroll
        for (int k = 0; k < K_; ++k) kacc[r][k] = 0.f;

#pragma unroll
    for (int ni = 0; ni < 4; ++ni) {
#pragma unroll
        for (int r = 0; r < 4; ++r) {
            float s = acc[ni][r] * qi[r] * di[ni];
#pragma unroll
            for (int k = 0; k < K_; ++k) {
                float df = s - MU_C[k];
                kacc[r][k] = fmaf(__expf(df * df * NEGC_C[k]), md[ni], kacc[r][k]);
            }
        }
    }
    // sum over the 16 d-lanes (low 4 lane bits; quad invariant)
#pragma unroll
    for (int m = 8; m >= 1; m >>= 1)
#pragma unroll
        for (int r = 0; r < 4; ++r)
#pragma unroll
            for (int k = 0; k < K_; ++k)
                kacc[r][k] += __shfl_xor(kacc[r][k], m);

    if (l15 == 0) {
        const size_t pbase = ((size_t)b * NCH + ch) * (LQ_ * K_);
#pragma unroll
        for (int r = 0; r < 4; ++r) {
            int q = wm * 16 + quad * 4 + r;
#pragma unroll
            for (int k = 0; k < K_; ++k) psum[pbase + q * K_ + k] = kacc[r][k];
        }
    }
}

// Combine chunk partials, log-pool, dense + tanh. One wave per batch.
__global__ __launch_bounds__(64) void knrm_final(
    const float* __restrict__ psum, const float* __restrict__ mask_q,
    const float* __restrict__ dw, const float* __restrict__ db,
    float* __restrict__ out)
{
    const int b = blockIdx.x;
    const int q = threadIdx.x;  // 0..63

    float t = 0.0f;
#pragma unroll
    for (int k = 0; k < K_; ++k) {
        float p = 0.0f;
#pragma unroll
        for (int c = 0; c < NCH; ++c)
            p += psum[(((size_t)b * NCH + c) * LQ_ + q) * K_ + k];
        p = fmaxf(p, 1e-10f);
        t += logf(p) * dw[k];
    }
    t *= 0.01f * mask_q[(size_t)b * LQ_ + q];

#pragma unroll
    for (int m = 32; m >= 1; m >>= 1) t += __shfl_xor(t, m);
    if (q == 0) out[b] = tanhf(t + db[0]);
}

extern "C" void kernel_launch(void* const* d_in, const int* in_sizes, int n_in,
                              void* d_out, int out_size, void* d_ws, size_t ws_size,
                              hipStream_t stream) {
    const float* Q   = (const float*)d_in[0];  // [B, LQ, E]
    const float* D   = (const float*)d_in[1];  // [B, LD, E]
    const float* mq  = (const float*)d_in[2];  // [B, LQ]
    const float* md  = (const float*)d_in[3];  // [B, LD]
    const float* dw  = (const float*)d_in[4];  // [1, K]
    const float* db  = (const float*)d_in[5];  // [1]
    float* out  = (float*)d_out;               // [B, 1]
    float* psum = (float*)d_ws;                // [B][NCH][LQ][K] = 2.75 MB

    dim3 grid(NCH, B_);
    knrm_main<<<grid, 256, 0, stream>>>(Q, D, md, psum);
    knrm_final<<<B_, 64, 0, stream>>>(psum, mq, dw, db, out);
}

// Round 4
// 148.126 us; speedup vs baseline: 1.4367x; 1.0217x over previous
//
#include <hip/hip_runtime.h>
#include <hip/hip_bf16.h>
#include <math.h>

#define B_   128
#define LQ_  64
#define LD_  512
#define E_   300
#define K_   11
#define NCH  4      // d-chunks per batch
#define DCH  128    // LD_/NCH
#define BK   32     // e-slice per MFMA step
#define NT   10     // k-steps (covers 320, zero-padded past 300)
#define QSTR 328    // Q LDS row stride in bf16 elems (320 data + 8 pad; 656B = 4 mod 32 dwords -> 2-way = free)
#define CSTR 130    // Cs LDS row stride in floats

typedef __bf16  bf16x8  __attribute__((ext_vector_type(8)));
typedef float   floatx4 __attribute__((ext_vector_type(4)));

__device__ __constant__ float MU_C[K_] =
    {1.0f, 0.9f, 0.7f, 0.5f, 0.3f, 0.1f, -0.1f, -0.3f, -0.5f, -0.7f, -0.9f};
__device__ __constant__ float NEGC_C[K_] =
    {-500000.0f, -50.0f, -50.0f, -50.0f, -50.0f, -50.0f,
     -50.0f, -50.0f, -50.0f, -50.0f, -50.0f};

__device__ __forceinline__ unsigned int pk2(float x, float y) {
    __hip_bfloat162 h = __float22bfloat162_rn(make_float2(x, y));
    union { __hip_bfloat162 h2; unsigned int u; } c;
    c.h2 = h;
    return c.u;
}

__device__ __forceinline__ void load8(const float* p, int e, float v[8]) {
    if (e + 8 <= E_) {
        float4 a = *(const float4*)(p + e);
        float4 b = *(const float4*)(p + e + 4);
        v[0] = a.x; v[1] = a.y; v[2] = a.z; v[3] = a.w;
        v[4] = b.x; v[5] = b.y; v[6] = b.z; v[7] = b.w;
    } else {
#pragma unroll
        for (int j = 0; j < 8; ++j) v[j] = (e + j < E_) ? p[e + j] : 0.0f;
    }
}

union __align__(16) ShBuf {
    unsigned short qs[LQ_ * QSTR];  // 41984 B  (K-loop: Q tiles, bf16)
    float          cs[LQ_ * CSTR];  // 33280 B  (epilogue: normalized sims)
};

// Fused GEMM + RBF pooling. Block = (batch, d-chunk of 128), 512 thr = 8 waves.
// Q staged to LDS ONCE (bf16); D streamed straight from global into MFMA
// B-fragments (lane l15 owns d-row, quad owns e-octet) -> NO barriers in K-loop.
// Wave w owns d-rows [d0+w*16, +16) x all 64 q (4 m-tiles of 16x16x32).
__global__ __launch_bounds__(512, 4) void knrm_main(
    const float* __restrict__ Q, const float* __restrict__ D,
    const float* __restrict__ mask_d, float* __restrict__ psum)
{
    const int b = blockIdx.y, ch = blockIdx.x, d0 = ch * DCH;
    const int tid  = threadIdx.x;
    const int lane = tid & 63;
    const int w    = tid >> 6;     // wave -> 16 d-rows
    const int quad = lane >> 4;
    const int l15  = lane & 15;

    __shared__ ShBuf sh;
    __shared__ float qinv_s[LQ_];
    __shared__ float md_s[DCH];

    // ---- one-time Q staging (fp32->bf16) + fused ssq; mask_d to LDS ----
    const int qrow = tid >> 3, qpart = tid & 7;   // 8 lanes per q-row
    const float* qp = Q + ((size_t)b * LQ_ + qrow) * E_;
    float ssq = 0.f;
#pragma unroll
    for (int j = 0; j < 10; ++j) {
        int e = qpart * 40 + j * 4;               // covers [0,320); zeros past 300
        float4 v = (e + 4 <= E_) ? *(const float4*)(qp + e)
                                 : make_float4(0.f, 0.f, 0.f, 0.f);
        ssq += v.x * v.x + v.y * v.y + v.z * v.z + v.w * v.w;
        *(uint2*)&sh.qs[qrow * QSTR + e] = make_uint2(pk2(v.x, v.y), pk2(v.z, v.w));
    }
    ssq += __shfl_xor(ssq, 1);
    ssq += __shfl_xor(ssq, 2);
    ssq += __shfl_xor(ssq, 4);
    if (qpart == 0) qinv_s[qrow] = 1.0f / fmaxf(sqrtf(ssq), 1e-12f);
    if (tid < DCH) md_s[tid] = mask_d[(size_t)b * LD_ + d0 + tid];

    // ---- barrier-free K-loop: D global -> bf16 frag -> MFMA ----
    const float* dp = D + ((size_t)b * LD_ + d0 + w * 16 + l15) * E_;
    floatx4 acc[4];
    floatx4 zero4 = {0.f, 0.f, 0.f, 0.f};
#pragma unroll
    for (int mt = 0; mt < 4; ++mt) acc[mt] = zero4;

    float ssd = 0.f;
    float dvc[8];
    load8(dp, quad * 8, dvc);       // tile 0 in flight before the barrier

    __syncthreads();                // Qs + qinv + md ready

#pragma unroll
    for (int t = 0; t < NT; ++t) {
        float dvn[8];
        if (t + 1 < NT) load8(dp, (t + 1) * BK + quad * 8, dvn);

#pragma unroll
        for (int j = 0; j < 8; ++j) ssd = fmaf(dvc[j], dvc[j], ssd);
        union { uint4 u; bf16x8 v; } bc;
        bc.u = make_uint4(pk2(dvc[0], dvc[1]), pk2(dvc[2], dvc[3]),
                          pk2(dvc[4], dvc[5]), pk2(dvc[6], dvc[7]));

        const int ebase = t * BK + quad * 8;
#pragma unroll
        for (int mt = 0; mt < 4; ++mt) {
            bf16x8 af = *(const bf16x8*)&sh.qs[(mt * 16 + l15) * QSTR + ebase];
            acc[mt] = __builtin_amdgcn_mfma_f32_16x16x32_bf16(af, bc.v, acc[mt], 0, 0, 0);
        }
        if (t + 1 < NT) {
#pragma unroll
            for (int j = 0; j < 8; ++j) dvc[j] = dvn[j];
        }
    }

    // d inv-norm: quads of same l15 covered disjoint e-octets
    ssd += __shfl_xor(ssd, 16);
    ssd += __shfl_xor(ssd, 32);
    const float dinv = 1.0f / fmaxf(sqrtf(ssd), 1e-12f);

    // ---- epilogue: normalized sims -> LDS (aliases Qs), repartition, pool ----
    __syncthreads();                // all Qs reads done before aliasing as Cs
#pragma unroll
    for (int mt = 0; mt < 4; ++mt) {
#pragma unroll
        for (int r = 0; r < 4; ++r) {
            int q = mt * 16 + quad * 4 + r;
            sh.cs[q * CSTR + w * 16 + l15] = acc[mt][r] * qinv_s[q] * dinv;
        }
    }
    __syncthreads();

    const int pq = tid >> 3, pd = tid & 7;   // thread: q-row x 16-d slice
    float kacc[K_];
#pragma unroll
    for (int k = 0; k < K_; ++k) kacc[k] = 0.f;
#pragma unroll
    for (int j = 0; j < 16; ++j) {
        float s = sh.cs[pq * CSTR + pd * 16 + j];
        float m = md_s[pd * 16 + j];
#pragma unroll
        for (int k = 0; k < K_; ++k) {
            float df = s - MU_C[k];
            kacc[k] = fmaf(__expf(df * df * NEGC_C[k]), m, kacc[k]);
        }
    }
#pragma unroll
    for (int msk = 1; msk <= 4; msk <<= 1)
#pragma unroll
        for (int k = 0; k < K_; ++k) kacc[k] += __shfl_xor(kacc[k], msk);

    if (pd == 0) {
        const size_t base = (((size_t)b * NCH + ch) * LQ_ + pq) * K_;
#pragma unroll
        for (int k = 0; k < K_; ++k) psum[base + k] = kacc[k];
    }
}

// Combine chunk partials, log-pool, dense + tanh. One wave per batch.
__global__ __launch_bounds__(64) void knrm_final(
    const float* __restrict__ psum, const float* __restrict__ mask_q,
    const float* __restrict__ dw, const float* __restrict__ db,
    float* __restrict__ out)
{
    const int b = blockIdx.x;
    const int q = threadIdx.x;  // 0..63

    float t = 0.0f;
#pragma unroll
    for (int k = 0; k < K_; ++k) {
        float p = 0.0f;
#pragma unroll
        for (int c = 0; c < NCH; ++c)
            p += psum[(((size_t)b * NCH + c) * LQ_ + q) * K_ + k];
        p = fmaxf(p, 1e-10f);
        t += logf(p) * dw[k];
    }
    t *= 0.01f * mask_q[(size_t)b * LQ_ + q];

#pragma unroll
    for (int m = 32; m >= 1; m >>= 1) t += __shfl_xor(t, m);
    if (q == 0) out[b] = tanhf(t + db[0]);
}

extern "C" void kernel_launch(void* const* d_in, const int* in_sizes, int n_in,
                              void* d_out, int out_size, void* d_ws, size_t ws_size,
                              hipStream_t stream) {
    const float* Q   = (const float*)d_in[0];  // [B, LQ, E]
    const float* D   = (const float*)d_in[1];  // [B, LD, E]
    const float* mq  = (const float*)d_in[2];  // [B, LQ]
    const float* md  = (const float*)d_in[3];  // [B, LD]
    const float* dw  = (const float*)d_in[4];  // [1, K]
    const float* db  = (const float*)d_in[5];  // [1]
    float* out  = (float*)d_out;               // [B, 1]
    float* psum = (float*)d_ws;                // [B][NCH][LQ][K] = 1.4 MB

    dim3 grid(NCH, B_);
    knrm_main<<<grid, 512, 0, stream>>>(Q, D, md, psum);
    knrm_final<<<B_, 64, 0, stream>>>(psum, mq, dw, db, out);
}